// Round 10
// baseline (22.357 us; speedup 1.0000x reference)
//
#include <hip/hip_runtime.h>

// Problem sizes (fixed by reference setup_inputs).
static constexpr int T_SZ = 4096;
static constexpr int N_SZ = 65536;

// Cosine-series (Poisson summation) Gauss transform.
// Natural units: x = (t - tt)/(0.1*sqrt(2)) in [-7.072, 7.072].
// Periodize exp(-x^2) with period 2L = 16 (image term ~2e-35):
//   exp(-x^2) = beta_0 + sum_{m=1..MORD} beta_m cos(m*pi*x/8)
//   beta_m = (sqrt(pi)/8) * exp(-(m*pi/16)^2)  (halved at m=0).
// MORD=18: tail < 3e-7 -> output error ~1e-5 (verified R8: absmax 3.05e-5).
static constexpr int MORD = 18;
static constexpr int NS   = 2 + 4 * MORD;   // 74 slots: A0,C0, then per m: A,B,C,D

#define OMT     2.7768018f            // (pi/8)/(0.1*sqrt(2)): radians per t-unit
#define L2E_H   0.7213475204444817f   // log2(e)/2
#define BETA_S  0.221556774f          // sqrt(pi)/8
#define BETA_K  0.055620402f          // (pi/16)^2 * log2(e)

static constexpr int NBLK = 256;            // one block per CU, 1 source/thread
static constexpr int NTHR = 256;
static constexpr int EVBLK = T_SZ / NTHR;   // 16 eval blocks

static constexpr unsigned MAGIC = 0x5ee0f00du;   // != 0xAAAAAAAA poison

// DPP wave-reduce: 4 row_shr stages give 16-lane row sums in lanes 15/31/47/63;
// row_bcast:15 + row_bcast:31 accumulate them into lane 63.
#define DPP_ADD(x, ctrl) \
    ((x) + __int_as_float(__builtin_amdgcn_update_dpp( \
        0, __float_as_int(x), (ctrl), 0xf, 0xf, true)))

__device__ __forceinline__ float wave_sum63(float x) {
    x = DPP_ADD(x, 0x111);   // row_shr:1
    x = DPP_ADD(x, 0x112);   // row_shr:2
    x = DPP_ADD(x, 0x114);   // row_shr:4
    x = DPP_ADD(x, 0x118);   // row_shr:8
    x = DPP_ADD(x, 0x142);   // row_bcast:15
    x = DPP_ADD(x, 0x143);   // row_bcast:31
    return x;                // lane 63 = wave sum
}

// ---------------------------------------------------------------------------
// Single-dispatch fused kernel.
//   All 256 blocks: Fourier moment partial for their 256 sources ->
//     partials[bid][NS] (plain store), release-store flags[bid]=MAGIC.
//   Blocks 0..15: wave 0 polls all 256 flags with RELAXED device-scope RMWs
//     (coherence-point reads, NO per-poll cache invalidate - R7's mistake),
//     one acquire fence after, then reduce partials and evaluate 256 rows.
// Producers never wait -> deadlock-free under any scheduling. Stale-MAGIC
// fast-path on replays is benign: partials are a deterministic function of
// the unmodified inputs, so any stale values read are bit-identical.
// ---------------------------------------------------------------------------
__global__ __launch_bounds__(NTHR) void fused_kernel(
        const float* __restrict__ target_t,
        const float* __restrict__ param_mat,
        const float* __restrict__ t_mat,
        const float* __restrict__ th_mat,
        const float* __restrict__ target_norm,
        const float* __restrict__ param_sigma,
        float* __restrict__ partials,
        unsigned* __restrict__ flags,
        float* __restrict__ out) {
    __shared__ float wsum[NTHR / 64][NS + 2];
    __shared__ float coef[NS];
    int tid = threadIdx.x;
    int bid = blockIdx.x;

    // ---- Phase 1: Fourier moments for this block's 256 sources -----------
    int n = bid * NTHR + tid;
    float4 pm = reinterpret_cast<const float4*>(param_mat)[n];
    float r0 = __builtin_amdgcn_rcpf(param_sigma[0]);
    float r1 = __builtin_amdgcn_rcpf(param_sigma[1]);
    float r2 = __builtin_amdgcn_rcpf(param_sigma[2]);
    float r3 = __builtin_amdgcn_rcpf(param_sigma[3]);
    float d0 = (pm.x - target_norm[0]) * r0;
    float d1 = (pm.y - target_norm[1]) * r1;
    float d2 = (pm.z - target_norm[2]) * r2;
    float d3 = (pm.w - target_norm[3]) * r3;
    float pd2 = d0*d0 + d1*d1 + d2*d2 + d3*d3;

    float c1 = __builtin_amdgcn_exp2f(-pd2 * L2E_H);
    float c2 = c1 * th_mat[n];

    float th = OMT * t_mat[n];
    float cv = __cosf(th);
    float sv = __sinf(th);

    float val[NS];
    val[0] = c1;
    val[1] = c2;
    {
        float cp = 1.0f, sp = 0.0f, cm = cv, sm = sv;
        #pragma unroll
        for (int m = 1; m <= MORD; ++m) {
            int b = 2 + 4 * (m - 1);
            val[b + 0] = c1 * cm;
            val[b + 1] = c1 * sm;
            val[b + 2] = c2 * cm;
            val[b + 3] = c2 * sm;
            float cn = fmaf(2.0f * cv, cm, -cp);   // cos((m+1)th)
            float sn = fmaf(2.0f * cv, sm, -sp);   // sin((m+1)th)
            cp = cm; cm = cn;
            sp = sm; sm = sn;
        }
    }

    #pragma unroll
    for (int s = 0; s < NS; ++s) val[s] = wave_sum63(val[s]);

    int lane = tid & 63, w = tid >> 6;
    if (lane == 63) {
        #pragma unroll
        for (int s = 0; s < NS; ++s) wsum[w][s] = val[s];
    }
    __syncthreads();
    if (tid < NS) {
        float s = wsum[0][tid] + wsum[1][tid] + wsum[2][tid] + wsum[3][tid];
        partials[bid * NS + tid] = s;
    }
    __syncthreads();
    if (tid == 0) {
        // Release at agent scope: writes back this block's partial past the
        // XCD L2, then publishes the flag at the coherence point.
        __hip_atomic_store(&flags[bid], MAGIC,
                           __ATOMIC_RELEASE, __HIP_MEMORY_SCOPE_AGENT);
    }

    // ---- Phase 2: blocks 0..15 wait (lightweight), reduce, evaluate ------
    if (bid >= EVBLK) return;

    if (tid < 64) {
        // Wave 0 polls 4 flags/lane with relaxed device-scope RMWs: reads the
        // coherence point directly (no stale-L2 deadlock), emits NO cache
        // invalidations (unlike acquire loads - the R7 35us pathology).
        for (;;) {
            unsigned f0 = __hip_atomic_fetch_or(&flags[tid],       0u,
                            __ATOMIC_RELAXED, __HIP_MEMORY_SCOPE_AGENT);
            unsigned f1 = __hip_atomic_fetch_or(&flags[tid +  64], 0u,
                            __ATOMIC_RELAXED, __HIP_MEMORY_SCOPE_AGENT);
            unsigned f2 = __hip_atomic_fetch_or(&flags[tid + 128], 0u,
                            __ATOMIC_RELAXED, __HIP_MEMORY_SCOPE_AGENT);
            unsigned f3 = __hip_atomic_fetch_or(&flags[tid + 192], 0u,
                            __ATOMIC_RELAXED, __HIP_MEMORY_SCOPE_AGENT);
            bool ok = (f0 == MAGIC) & (f1 == MAGIC) &
                      (f2 == MAGIC) & (f3 == MAGIC);
            if (__all(ok)) break;
            __builtin_amdgcn_s_sleep(2);
        }
    }
    __syncthreads();
    // Single acquire fence at agent scope: invalidate stale cache lines so
    // the plain loads of partials below observe the producers' released data.
    __builtin_amdgcn_fence(__ATOMIC_ACQUIRE, "agent");

    if (tid < NS) {
        float s = 0.0f;
        #pragma unroll 8
        for (int p = 0; p < NBLK; ++p) s += partials[p * NS + tid];
        int m = (tid < 2) ? 0 : ((tid - 2) >> 2) + 1;
        float beta = BETA_S * __builtin_amdgcn_exp2f(-BETA_K * (float)(m * m));
        if (m == 0) beta *= 0.5f;
        coef[tid] = s * beta;
    }
    __syncthreads();

    int t = bid * NTHR + tid;
    float thv = OMT * target_t[t];
    float cvv = __cosf(thv);
    float svv = __sinf(thv);

    float den = coef[0];
    float num = coef[1];
    float cp = 1.0f, sp = 0.0f, cm = cvv, sm = svv;
    #pragma unroll
    for (int m = 1; m <= MORD; ++m) {
        int b = 2 + 4 * (m - 1);
        den = fmaf(coef[b + 0], cm, den);
        den = fmaf(coef[b + 1], sm, den);
        num = fmaf(coef[b + 2], cm, num);
        num = fmaf(coef[b + 3], sm, num);
        float cn = fmaf(2.0f * cvv, cm, -cp);
        float sn = fmaf(2.0f * cvv, sm, -sp);
        cp = cm; cm = cn;
        sp = sm; sm = sn;
    }
    out[t] = num / den;
}

// ---------------------------------------------------------------------------
extern "C" void kernel_launch(void* const* d_in, const int* in_sizes, int n_in,
                              void* d_out, int out_size, void* d_ws, size_t ws_size,
                              hipStream_t stream) {
    const float* target_t    = (const float*)d_in[0];  // [T,1]
    const float* param_mat   = (const float*)d_in[1];  // [N,4]
    const float* t_mat       = (const float*)d_in[2];  // [N]
    const float* th_mat      = (const float*)d_in[3];  // [N]
    const float* target_norm = (const float*)d_in[4];  // [4]
    const float* param_sigma = (const float*)d_in[5];  // [4]
    float* out = (float*)d_out;                        // [1,T] -> 4096 f32

    char* ws = (char*)d_ws;
    float*    partials = (float*)ws;                        // 256*74 f = 76 KB
    unsigned* flags    = (unsigned*)(ws + NBLK * NS * 4);   // 1 KB

    fused_kernel<<<NBLK, NTHR, 0, stream>>>(target_t, param_mat, t_mat,
                                            th_mat, target_norm, param_sigma,
                                            partials, flags, out);
}

// Round 11
// 20.698 us; speedup vs baseline: 1.0801x; 1.0801x over previous
//
#include <hip/hip_runtime.h>

// Problem sizes (fixed by reference setup_inputs).
static constexpr int T_SZ = 4096;
static constexpr int N_SZ = 65536;

// Cosine-series (Poisson summation) Gauss transform.
// Natural units: x = (t - tt)/(0.1*sqrt(2)) in [-7.072, 7.072].
// Periodize exp(-x^2) with period 2L = 16 (image term exp(-8.93^2) ~ 2e-35):
//   exp(-x^2) = beta_0 + sum_{m=1..MORD} beta_m cos(m*pi*x/8)
//   beta_m = (sqrt(pi)/8) * exp(-(m*pi/16)^2),  beta_0 half of that at m=0.
// MORD=18: tail < 3e-7 -> output error ~1e-5 (verified R8: absmax 3.05e-5).
// No boxes, no data-dependent indexing -> no LDS atomics (R4/R5 bottleneck).
static constexpr int MORD = 18;
static constexpr int NS   = 2 + 4 * MORD;   // 74 slots: A0,C0, then per m: A,B,C,D

#define OMT     2.7768018f     // (pi/8)*(1/(0.1*sqrt(2))): radians per t-unit
#define L2E_H   0.7213475204444817f   // log2(e)/2
#define BETA_S  0.221556774f   // sqrt(pi)/8
#define BETA_K  0.055620402f   // (pi/16)^2 * log2(e)

static constexpr int MBLK = 256;   // moments: 256 blocks x 256 thr, 1 source/thread
static constexpr int MTHR = 256;
static constexpr int EBLK = T_SZ / 256;   // 16 eval blocks

// DPP wave-reduce: after 4 row_shr stages each row's lane15/31/47/63 holds its
// row sum; row_bcast:15 then row_bcast:31 accumulate into lane 63 (total).
#define DPP_ADD(x, ctrl) \
    ((x) + __int_as_float(__builtin_amdgcn_update_dpp( \
        0, __float_as_int(x), (ctrl), 0xf, 0xf, true)))

__device__ __forceinline__ float wave_sum63(float x) {
    x = DPP_ADD(x, 0x111);   // row_shr:1
    x = DPP_ADD(x, 0x112);   // row_shr:2
    x = DPP_ADD(x, 0x114);   // row_shr:4
    x = DPP_ADD(x, 0x118);   // row_shr:8
    x = DPP_ADD(x, 0x142);   // row_bcast:15
    x = DPP_ADD(x, 0x143);   // row_bcast:31
    return x;                // lane 63 = wave sum
}

// ---------------------------------------------------------------------------
// Kernel 1: Fourier moments. Per source n:
//   c1 = exp(-pd2/2), c2 = c1*th, theta = OMT*t_mat[n]
//   val slots: {c1, c2} and per m: {c1*cos(m th), c1*sin, c2*cos, c2*sin}
// DPP wave reduce -> LDS (4 waves) -> plain store partials[block][slot].
// ---------------------------------------------------------------------------
__global__ __launch_bounds__(MTHR) void moments_kernel(
        const float* __restrict__ param_mat,
        const float* __restrict__ t_mat,
        const float* __restrict__ th_mat,
        const float* __restrict__ target_norm,
        const float* __restrict__ param_sigma,
        float* __restrict__ partials) {
    __shared__ float wsum[MTHR / 64][NS + 2];
    int tid = threadIdx.x;
    int n = blockIdx.x * MTHR + tid;

    float4 pm = reinterpret_cast<const float4*>(param_mat)[n];
    float r0 = __builtin_amdgcn_rcpf(param_sigma[0]);
    float r1 = __builtin_amdgcn_rcpf(param_sigma[1]);
    float r2 = __builtin_amdgcn_rcpf(param_sigma[2]);
    float r3 = __builtin_amdgcn_rcpf(param_sigma[3]);
    float d0 = (pm.x - target_norm[0]) * r0;
    float d1 = (pm.y - target_norm[1]) * r1;
    float d2 = (pm.z - target_norm[2]) * r2;
    float d3 = (pm.w - target_norm[3]) * r3;
    float pd2 = d0*d0 + d1*d1 + d2*d2 + d3*d3;

    float c1 = __builtin_amdgcn_exp2f(-pd2 * L2E_H);
    float c2 = c1 * th_mat[n];

    float th = OMT * t_mat[n];
    float cv = __cosf(th);
    float sv = __sinf(th);

    float val[NS];
    val[0] = c1;
    val[1] = c2;
    float cp = 1.0f, sp = 0.0f, cm = cv, sm = sv;
    #pragma unroll
    for (int m = 1; m <= MORD; ++m) {
        int b = 2 + 4 * (m - 1);
        val[b + 0] = c1 * cm;
        val[b + 1] = c1 * sm;
        val[b + 2] = c2 * cm;
        val[b + 3] = c2 * sm;
        float cn = fmaf(2.0f * cv, cm, -cp);   // cos((m+1)th)
        float sn = fmaf(2.0f * cv, sm, -sp);   // sin((m+1)th)
        cp = cm; cm = cn;
        sp = sm; sm = sn;
    }

    #pragma unroll
    for (int s = 0; s < NS; ++s) val[s] = wave_sum63(val[s]);

    int lane = tid & 63, w = tid >> 6;
    if (lane == 63) {
        #pragma unroll
        for (int s = 0; s < NS; ++s) wsum[w][s] = val[s];
    }
    __syncthreads();
    if (tid < NS) {
        float s = wsum[0][tid] + wsum[1][tid] + wsum[2][tid] + wsum[3][tid];
        partials[blockIdx.x * NS + tid] = s;
    }
}

// ---------------------------------------------------------------------------
// Kernel 2: reduce 256 partials, fold beta_m in, evaluate one row per thread:
//   den = sum_m beta_m [A_m cos(m thv) + B_m sin(m thv)],  num likewise (C,D).
// ---------------------------------------------------------------------------
__global__ __launch_bounds__(256) void eval_kernel(
        const float* __restrict__ target_t,
        const float* __restrict__ partials,
        float* __restrict__ out) {
    __shared__ float coef[NS];
    int tid = threadIdx.x;
    if (tid < NS) {
        float s = 0.0f;
        #pragma unroll 8
        for (int p = 0; p < MBLK; ++p) s += partials[p * NS + tid];
        int m = (tid < 2) ? 0 : ((tid - 2) >> 2) + 1;
        float beta = BETA_S * __builtin_amdgcn_exp2f(-BETA_K * (float)(m * m));
        if (m == 0) beta *= 0.5f;
        coef[tid] = s * beta;
    }
    __syncthreads();

    int t = blockIdx.x * 256 + tid;
    float th = OMT * target_t[t];
    float cv = __cosf(th);
    float sv = __sinf(th);

    float den = coef[0];
    float num = coef[1];
    float cp = 1.0f, sp = 0.0f, cm = cv, sm = sv;
    #pragma unroll
    for (int m = 1; m <= MORD; ++m) {
        int b = 2 + 4 * (m - 1);
        den = fmaf(coef[b + 0], cm, den);
        den = fmaf(coef[b + 1], sm, den);
        num = fmaf(coef[b + 2], cm, num);
        num = fmaf(coef[b + 3], sm, num);
        float cn = fmaf(2.0f * cv, cm, -cp);
        float sn = fmaf(2.0f * cv, sm, -sp);
        cp = cm; cm = cn;
        sp = sm; sm = sn;
    }
    out[t] = num / den;
}

// ---------------------------------------------------------------------------
extern "C" void kernel_launch(void* const* d_in, const int* in_sizes, int n_in,
                              void* d_out, int out_size, void* d_ws, size_t ws_size,
                              hipStream_t stream) {
    const float* target_t    = (const float*)d_in[0];  // [T,1]
    const float* param_mat   = (const float*)d_in[1];  // [N,4]
    const float* t_mat       = (const float*)d_in[2];  // [N]
    const float* th_mat      = (const float*)d_in[3];  // [N]
    const float* target_norm = (const float*)d_in[4];  // [4]
    const float* param_sigma = (const float*)d_in[5];  // [4]
    float* out = (float*)d_out;                        // [1,T] -> 4096 f32

    float* partials = (float*)d_ws;                    // 256*74 floats = 76 KB

    moments_kernel<<<MBLK, MTHR, 0, stream>>>(param_mat, t_mat, th_mat,
                                              target_norm, param_sigma,
                                              partials);
    eval_kernel<<<EBLK, 256, 0, stream>>>(target_t, partials, out);
}